// Round 15
// baseline (93.490 us; speedup 1.0000x reference)
//
#include <hip/hip_runtime.h>
#include <hip/hip_bf16.h>

// EDMultiheadRetention: S=128, D=4096, H=32, hd=128
// Pipeline: prep (cast x + kvsT) -> gemm_fused (KS=1, 192x512; A 3-buf 2-ahead via
//           global_load_lds (L2-cached); W NON-TEMPORAL f32 regs 2-ahead; fused
//           decay epilogue) -> heads
// R11 change vs R10: W loads use nt (no L2 allocation) so the 201 MB W stream
// stops evicting the 1 MB xb working set from per-XCD L2.

typedef __bf16 bf16x8 __attribute__((ext_vector_type(8)));
typedef float f32x4 __attribute__((ext_vector_type(4)));
typedef float f32x4e __attribute__((ext_vector_type(4)));  // for nontemporal loads

typedef __attribute__((address_space(1))) const unsigned g_u32;
typedef __attribute__((address_space(3))) unsigned l_u32;

static __device__ __forceinline__ f32x4 mfma_bf16(bf16x8 a, bf16x8 b, f32x4 c) {
  return __builtin_amdgcn_mfma_f32_16x16x32_bf16(a, b, c, 0, 0, 0);
}

static __device__ __forceinline__ bf16x8 cvt8(float4 lo, float4 hi) {
  return (bf16x8){(__bf16)lo.x, (__bf16)lo.y, (__bf16)lo.z, (__bf16)lo.w,
                  (__bf16)hi.x, (__bf16)hi.y, (__bf16)hi.z, (__bf16)hi.w};
}

static __device__ __forceinline__ bf16x8 cvt8v(f32x4e lo, f32x4e hi) {
  return (bf16x8){(__bf16)lo[0], (__bf16)lo[1], (__bf16)lo[2], (__bf16)lo[3],
                  (__bf16)hi[0], (__bf16)hi[1], (__bf16)hi[2], (__bf16)hi[3]};
}

#define WAIT_VM0() asm volatile("s_waitcnt vmcnt(0)" ::: "memory")
#define WAIT_VM4() asm volatile("s_waitcnt vmcnt(4)" ::: "memory")
#define WAIT_LGKM0() asm volatile("s_waitcnt lgkmcnt(0)" ::: "memory")
#define SCHED_FENCE() __builtin_amdgcn_sched_barrier(0)

// ---------------- kernel 1: cast x -> bf16 (blocks 0..255), kvsT prep (256..383)
__global__ __launch_bounds__(256) void prep_kernel(const float* __restrict__ x,
                                                   __bf16* __restrict__ xb,
                                                   const float* __restrict__ kvs,
                                                   const float* __restrict__ alpha,
                                                   __bf16* __restrict__ kvsT) {
  __shared__ float lds[32][129];
  const int tid = threadIdx.x;
  if (blockIdx.x < 256) {
    const int i = (blockIdx.x * 256 + tid) * 8;
    float4 a = *(const float4*)(x + i);
    float4 b = *(const float4*)(x + i + 4);
    *(bf16x8*)(xb + i) = cvt8(a, b);
    return;
  }
  const int bid = blockIdx.x - 256;
  const int h = bid >> 2, dq = bid & 3;
  const int j = tid & 127, dg = tid >> 7;
  const int d0 = dq * 32;
#pragma unroll
  for (int i = 0; i < 16; ++i) {
    const int dloc = dg * 16 + i;
    const int d = d0 + dloc;
    const float dS = exp2f(128.f * log2f(alpha[h * 128 + d]));
    lds[dloc][j] = kvs[(size_t)h * 16384 + d * 128 + j] * dS;
  }
  __syncthreads();
  const int jj = tid >> 1, dh = tid & 1;
  bf16x8 a0, a1;
#pragma unroll
  for (int i = 0; i < 8; ++i) a0[i] = (__bf16)lds[dh * 16 + i][jj];
#pragma unroll
  for (int i = 0; i < 8; ++i) a1[i] = (__bf16)lds[dh * 16 + 8 + i][jj];
  *(bf16x8*)(kvsT + (size_t)h * 16384 + jj * 128 + d0 + dh * 16) = a0;
  *(bf16x8*)(kvsT + (size_t)h * 16384 + jj * 128 + d0 + dh * 16 + 8) = a1;
}

// ---------------- kernel 2: single-pass GEMM + fused decay/layout epilogue ---
// 192 blocks x 512 thr (8 waves: 4 wm x 2 wn). Tile M=128 x N=64, K=4096, BK=64.
// A: global_load_lds (L2-allocating), XOR-swizzled, 3 buffers, issued 2 iters ahead.
// W: NON-TEMPORAL f32 reg loads, issued 2 iters ahead; cvt->ds_write 1 iter ahead.
// Steady state: one vmcnt(4) per iter drains A(T+1)+W(T+1), keeps T+2 in flight.
__global__ __launch_bounds__(512, 2) void gemm_fused_kernel(const __bf16* __restrict__ xb,
                                                            const float* __restrict__ W,
                                                            const float* __restrict__ alpha,
                                                            __bf16* __restrict__ qd,
                                                            __bf16* __restrict__ kd,
                                                            __bf16* __restrict__ kdT,
                                                            __bf16* __restrict__ vT) {
  __shared__ __bf16 Ald[3][128 * 64];  // 48 KB
  __shared__ __bf16 Bld[2][64 * 64];   // 16 KB

  const int tid = threadIdx.x;
  const int wid = tid >> 6, lane = tid & 63;
  const int r0 = lane & 15, l4 = lane >> 4, rr = l4 << 2;
  const int n0 = blockIdx.x * 64;
  const int wm = wid & 3, wn = wid >> 2;

  // A staging: 2 DMA units/thread; unit u -> (row=u>>3, phys chunk p=u&7),
  // source logical chunk g = p ^ (row&7); LDS dest linear (u*16 B).
  int a_row[2], a_koff[2];
#pragma unroll
  for (int i = 0; i < 2; ++i) {
    const int u = i * 512 + tid;
    a_row[i] = u >> 3;
    a_koff[i] = ((u & 7) ^ (a_row[i] & 7)) << 3;
  }
  // B staging: 1 unit/thread (64 rows x 8 chunks = 512 units)
  const int b_row = tid >> 3, b_p = tid & 7;
  const int b_elem = b_row * 64 + b_p * 8;
  // W pointer in float4 units (16B aligned): row*4096 + swizzled 8-float chunk
  const f32x4e* wp4 =
      (const f32x4e*)(W + (size_t)(n0 + b_row) * 4096 + ((b_p ^ (b_row & 7)) << 3));

  // fragment read offsets (elements): logical chunk c = kh*4+l4, phys = c^(row&7)
  int a_off[2][2], b_off[2][2];
#pragma unroll
  for (int mf = 0; mf < 2; ++mf)
#pragma unroll
    for (int kh = 0; kh < 2; ++kh) {
      const int row = wm * 32 + mf * 16 + r0;
      const int p = (kh * 4 + l4) ^ (row & 7);
      a_off[mf][kh] = row * 64 + p * 8;
    }
#pragma unroll
  for (int nf = 0; nf < 2; ++nf)
#pragma unroll
    for (int kh = 0; kh < 2; ++kh) {
      const int row = wn * 32 + nf * 16 + r0;
      const int p = (kh * 4 + l4) ^ (row & 7);
      b_off[nf][kh] = row * 64 + p * 8;
    }

  f32x4 acc[2][2];
#pragma unroll
  for (int mf = 0; mf < 2; ++mf)
#pragma unroll
    for (int nf = 0; nf < 2; ++nf) acc[mf][nf] = (f32x4){0.f, 0.f, 0.f, 0.f};

  f32x4e w0lo, w0hi, w1lo, w1hi;  // set[T&1] holds W(T) until its ds_write

#define A_ISSUE(T_, BUF_)                                                        \
  do {                                                                           \
    const int kb_ = (T_) * 64;                                                   \
    char* dst_ = (char*)&Ald[0][0] + (BUF_) * 16384;                             \
    _Pragma("unroll") for (int i = 0; i < 2; ++i) {                              \
      const __bf16* src = xb + a_row[i] * 4096 + kb_ + a_koff[i];                \
      __builtin_amdgcn_global_load_lds((g_u32*)(const void*)src,                 \
          (l_u32*)(void*)(dst_ + i * 8192 + wid * 1024), 16, 0, 0);              \
    }                                                                            \
  } while (0)

// W tile T starts at float offset T*64 = float4 offset T*16
#define W_LOAD_LO(T_) __builtin_nontemporal_load(wp4 + ((T_) << 4))
#define W_LOAD_HI(T_) __builtin_nontemporal_load(wp4 + ((T_) << 4) + 1)

  // ---- prologue. Issue order (FIFO): A(0), W(0), A(1), W(1).
  A_ISSUE(0, 0);
  w0lo = W_LOAD_LO(0);
  w0hi = W_LOAD_HI(0);
  A_ISSUE(1, 1);
  w1lo = W_LOAD_LO(1);
  w1hi = W_LOAD_HI(1);
  WAIT_VM4();  // A(0)+W(0) done; A(1)+W(1) in flight
  *(bf16x8*)(&Bld[0][b_elem]) = cvt8v(w0lo, w0hi);
  WAIT_LGKM0();
  SCHED_FENCE();
  __builtin_amdgcn_s_barrier();
  SCHED_FENCE();

// Iter T: issue A(T+2)->BUFN2 and W(T+2)->LD set; compute from BUFC/Bld[CURB];
// wait vmcnt(4) (A(T+1)+W(T+1) landed, T+2 stays in flight); ds_write B(T+1); barrier.
#define GEMM_ITER(T, BUFC, BUFN2, CURB, WRLO, WRHI, LDLO, LDHI)                  \
  do {                                                                           \
    const bool hn1 = (T) + 1 < 64, hn2 = (T) + 2 < 64;                           \
    if (hn2) {                                                                   \
      A_ISSUE((T) + 2, BUFN2);                                                   \
      LDLO = W_LOAD_LO((T) + 2);                                                 \
      LDHI = W_LOAD_HI((T) + 2);                                                 \
    }                                                                            \
    SCHED_FENCE();                                                               \
    const __bf16* abase_ = &Ald[0][0] + (BUFC) * 8192;                           \
    bf16x8 af[2][2], bfr[2][2];                                                  \
    _Pragma("unroll") for (int kh = 0; kh < 2; ++kh) {                           \
      _Pragma("unroll") for (int mf = 0; mf < 2; ++mf)                           \
          af[mf][kh] = *(const bf16x8*)(abase_ + a_off[mf][kh]);                 \
      _Pragma("unroll") for (int nf = 0; nf < 2; ++nf)                           \
          bfr[nf][kh] = *(const bf16x8*)(&Bld[CURB][b_off[nf][kh]]);             \
    }                                                                            \
    _Pragma("unroll") for (int kh = 0; kh < 2; ++kh)                             \
        _Pragma("unroll") for (int mf = 0; mf < 2; ++mf)                         \
            _Pragma("unroll") for (int nf = 0; nf < 2; ++nf)                     \
                acc[mf][nf] = mfma_bf16(af[mf][kh], bfr[nf][kh], acc[mf][nf]);   \
    SCHED_FENCE();                                                               \
    if (hn1) {                                                                   \
      if (hn2) { WAIT_VM4(); } else { WAIT_VM0(); } /* A,W(T+1) landed */        \
      *(bf16x8*)(&Bld[1 - (CURB)][b_elem]) = cvt8v(WRLO, WRHI);                  \
      WAIT_LGKM0();                                                              \
      SCHED_FENCE();                                                             \
      __builtin_amdgcn_s_barrier();                                              \
      SCHED_FENCE();                                                             \
    }                                                                            \
  } while (0)

  {
    int bA = 0;  // buffer holding A(t) at even-iter entry
    for (int t = 0; t < 64; t += 2) {
      int bB = bA + 1; if (bB >= 3) bB = 0;  // holds A(t+1)
      int bC = bB + 1; if (bC >= 3) bC = 0;  // free -> receives A(t+2)
      GEMM_ITER(t, bA, bC, 0, w1lo, w1hi, w0lo, w0hi);
      GEMM_ITER(t + 1, bB, bA, 1, w0lo, w0hi, w1lo, w1hi);  // A(t+3) -> bA
      bA = bC;
    }
  }
#undef GEMM_ITER
#undef A_ISSUE
#undef W_LOAD_LO
#undef W_LOAD_HI

  // ---- fused epilogue: acc -> LDS f32 -> decay -> bf16 layouts
  __syncthreads();  // all A/B LDS reads done; safe to repurpose Ald
  float* LDSf = (float*)&Ald[0][0];  // 128 x 64 f32 = 32 KB
#pragma unroll
  for (int mf = 0; mf < 2; ++mf)
#pragma unroll
    for (int nf = 0; nf < 2; ++nf)
#pragma unroll
      for (int r = 0; r < 4; ++r) {
        const int s = wm * 32 + mf * 16 + rr + r;
        const int c = wn * 32 + nf * 16 + r0;
        LDSf[s * 64 + c] = acc[mf][nf][r];
      }
  __syncthreads();

  const int which = n0 >> 12;      // 0=q 1=k 2=v
  const int hd = n0 & 4095;
  const int h = hd >> 7;
  const int db = hd & 127;         // 0 or 64

  if (which < 2) {
    // row-major [h][s][db..db+64): unit u = (s, 8d)
    __bf16* dst = (which == 0 ? qd : kd) + (size_t)h * 16384;
#pragma unroll
    for (int i = 0; i < 2; ++i) {
      const int u = i * 512 + tid;
      const int s = u >> 3, d8 = (u & 7) * 8;
      bf16x8 frag;
#pragma unroll
      for (int j = 0; j < 8; ++j) {
        const float la = log2f(alpha[h * 128 + db + d8 + j]);
        const float e = (which == 0) ? (float)(s - 127) : (float)(127 - s);
        frag[j] = (__bf16)(LDSf[s * 64 + d8 + j] * exp2f(e * la - 6.0f));
      }
      *(bf16x8*)(dst + s * 128 + db + d8) = frag;
    }
  }
  if (which >= 1) {
    // transposed [h][db+d][s]: unit u = (d, 8s)
    __bf16* dstT = (which == 1 ? kdT : vT) + (size_t)h * 16384;
#pragma unroll
    for (int i = 0; i < 2; ++i) {
      const int u = i * 512 + tid;
      const int d = u >> 4, s8 = (u & 15) * 8;
      bf16x8 frag;
      if (which == 1) {
        const float la = log2f(alpha[h * 128 + db + d]);
#pragma unroll
        for (int j = 0; j < 8; ++j)
          frag[j] = (__bf16)(LDSf[(s8 + j) * 64 + d] * exp2f((float)(127 - (s8 + j)) * la - 6.0f));
      } else {
#pragma unroll
        for (int j = 0; j < 8; ++j) frag[j] = (__bf16)LDSf[(s8 + j) * 64 + d];
      }
      *(bf16x8*)(dstT + (db + d) * 128 + s8) = frag;
    }
  }
}

// ---------------- kernel 3: per-head retention (all contiguous bf16 loads) --
// bid<128: out rows; bid>=128: new_kvs rows. 128 threads (2 waves).
__global__ __launch_bounds__(128) void heads_kernel(const __bf16* __restrict__ qd,
                                                    const __bf16* __restrict__ kd,
                                                    const __bf16* __restrict__ kdT,
                                                    const __bf16* __restrict__ vT,
                                                    const __bf16* __restrict__ kvsT,
                                                    const float* __restrict__ kvs,
                                                    const float* __restrict__ alpha,
                                                    float* __restrict__ out) {
  const int bid = blockIdx.x;
  const int tid = threadIdx.x;
  const int wid = tid >> 6, lane = tid & 63;
  const int r0 = lane & 15, l4 = lane >> 4;
  const int g8 = l4 << 3, rr = l4 << 2;

  if (bid < 128) {
    const int h = bid >> 2, w = bid & 3;
    const int m_base = w * 32;
    __shared__ __bf16 attn_s[32][136];
    const __bf16* qh = qd + (size_t)h * 16384;
    const __bf16* kh = kd + (size_t)h * 16384;

    f32x4 acc[2][4];
#pragma unroll
    for (int mf = 0; mf < 2; ++mf)
#pragma unroll
      for (int nf = 0; nf < 4; ++nf) acc[mf][nf] = (f32x4){0.f, 0.f, 0.f, 0.f};

    // phase 1: attn cols wid*64..+64
#pragma unroll
    for (int k0 = 0; k0 < 128; k0 += 32) {
      const int kk = k0 + g8;
      bf16x8 a[2];
#pragma unroll
      for (int mf = 0; mf < 2; ++mf)
        a[mf] = *(const bf16x8*)(qh + (m_base + mf * 16 + r0) * 128 + kk);
#pragma unroll
      for (int nf = 0; nf < 4; ++nf) {
        const int jn = wid * 64 + nf * 16 + r0;
        bf16x8 b = *(const bf16x8*)(kh + jn * 128 + kk);
#pragma unroll
        for (int mf = 0; mf < 2; ++mf) acc[mf][nf] = mfma_bf16(a[mf], b, acc[mf][nf]);
      }
    }
#pragma unroll
    for (int mf = 0; mf < 2; ++mf)
#pragma unroll
      for (int nf = 0; nf < 4; ++nf)
#pragma unroll
        for (int r = 0; r < 4; ++r) {
          const int i = m_base + mf * 16 + rr + r;
          const int j = wid * 64 + nf * 16 + r0;
          attn_s[mf * 16 + rr + r][j] = (__bf16)((j <= i) ? acc[mf][nf][r] : 0.f);
        }
    __syncthreads();

    // phase 2: out = gelu(attn @ v + q @ kvsT), d2 in wid*64..+64
#pragma unroll
    for (int mf = 0; mf < 2; ++mf)
#pragma unroll
      for (int nf = 0; nf < 4; ++nf) acc[mf][nf] = (f32x4){0.f, 0.f, 0.f, 0.f};
    const __bf16* vTh = vT + (size_t)h * 16384;
    const __bf16* kvsTh = kvsT + (size_t)h * 16384;
#pragma unroll
    for (int k0 = 0; k0 < 128; k0 += 32) {
      const int kk = k0 + g8;
      bf16x8 a[2];
#pragma unroll
      for (int mf = 0; mf < 2; ++mf)
        a[mf] = *(const bf16x8*)(&attn_s[mf * 16 + r0][kk]);
#pragma unroll
      for (int nf = 0; nf < 4; ++nf) {
        const int d2 = wid * 64 + nf * 16 + r0;
        bf16x8 b = *(const bf16x8*)(vTh + d2 * 128 + kk);
#pragma unroll
        for (int mf = 0; mf < 2; ++mf) acc[mf][nf] = mfma_bf16(a[mf], b, acc[mf][nf]);
      }
    }
#pragma unroll
    for (int k0 = 0; k0 < 128; k0 += 32) {
      const int kk = k0 + g8;
      bf16x8 a[2];
#pragma unroll
      for (int mf = 0; mf < 2; ++mf)
        a[mf] = *(const bf16x8*)(qh + (m_base + mf * 16 + r0) * 128 + kk);
#pragma unroll
      for (int nf = 0; nf < 4; ++nf) {
        const int d2 = wid * 64 + nf * 16 + r0;
        bf16x8 b = *(const bf16x8*)(kvsTh + d2 * 128 + kk);
#pragma unroll
        for (int mf = 0; mf < 2; ++mf) acc[mf][nf] = mfma_bf16(a[mf], b, acc[mf][nf]);
      }
    }
#pragma unroll
    for (int mf = 0; mf < 2; ++mf)
#pragma unroll
      for (int nf = 0; nf < 4; ++nf)
#pragma unroll
        for (int r = 0; r < 4; ++r) {
          const int s = m_base + mf * 16 + rr + r;
          const int d2 = wid * 64 + nf * 16 + r0;
          const float y = acc[mf][nf][r];
          const float u = 0.7978845608028654f * (y + 0.044715f * y * y * y);
          out[(size_t)s * 4096 + h * 128 + d2] = 0.5f * y * (1.f + tanhf(u));
        }
  } else {
    const int b2 = bid - 128;
    const int h = b2 >> 2, w = b2 & 3;
    const int m_base = w * 32;
    const __bf16* kTh = kdT + (size_t)h * 16384;
    const __bf16* vTh = vT + (size_t)h * 16384;

    f32x4 acc[2][4];
#pragma unroll
    for (int mf = 0; mf < 2; ++mf)
#pragma unroll
      for (int nf = 0; nf < 4; ++nf) acc[mf][nf] = (f32x4){0.f, 0.f, 0.f, 0.f};
#pragma unroll
    for (int k0 = 0; k0 < 128; k0 += 32) {
      const int kk = k0 + g8;
      bf16x8 a[2];
#pragma unroll
      for (int mf = 0; mf < 2; ++mf)
        a[mf] = *(const bf16x8*)(kTh + (m_base + mf * 16 + r0) * 128 + kk);
#pragma unroll
      for (int nf = 0; nf < 4; ++nf) {
        const int j = wid * 64 + nf * 16 + r0;
        bf16x8 b = *(const bf16x8*)(vTh + j * 128 + kk);
#pragma unroll
        for (int mf = 0; mf < 2; ++mf) acc[mf][nf] = mfma_bf16(a[mf], b, acc[mf][nf]);
      }
    }
#pragma unroll
    for (int mf = 0; mf < 2; ++mf)
#pragma unroll
      for (int nf = 0; nf < 4; ++nf)
#pragma unroll
        for (int r = 0; r < 4; ++r) {
          const int i = m_base + mf * 16 + rr + r;
          const int j = wid * 64 + nf * 16 + r0;
          const float dSi = exp2f(128.f * log2f(alpha[h * 128 + i]));
          const float val = acc[mf][nf][r] + kvs[(size_t)h * 16384 + i * 128 + j] * dSi;
          out[524288 + (size_t)h * 16384 + i * 128 + j] = val;
        }
  }
}

extern "C" void kernel_launch(void* const* d_in, const int* in_sizes, int n_in,
                              void* d_out, int out_size, void* d_ws, size_t ws_size,
                              hipStream_t stream) {
  const float* x = (const float*)d_in[0];      // (128, 4096)
  const float* W = (const float*)d_in[1];      // (12288, 4096)
  const float* alpha = (const float*)d_in[2];  // (32, 128)
  const float* kvs = (const float*)d_in[3];    // (32, 128, 128)
  float* out = (float*)d_out;

  char* ws = (char*)d_ws;
  __bf16* xb = (__bf16*)ws;                      // 1 MB
  __bf16* qd = (__bf16*)(ws + (1u << 20));       // 1 MB each
  __bf16* kd = (__bf16*)(ws + 2u * (1u << 20));
  __bf16* kdT = (__bf16*)(ws + 3u * (1u << 20));
  __bf16* vT = (__bf16*)(ws + 4u * (1u << 20));
  __bf16* kvsT = (__bf16*)(ws + 5u * (1u << 20));

  prep_kernel<<<384, 256, 0, stream>>>(x, xb, kvs, alpha, kvsT);
  gemm_fused_kernel<<<192, 512, 0, stream>>>(xb, W, alpha, qd, kd, kdT, vT);
  heads_kernel<<<256, 128, 0, stream>>>(qd, kd, kdT, vT, kvsT, kvs, alpha, out);
}

// Round 16
// 65.303 us; speedup vs baseline: 1.4316x; 1.4316x over previous
//
#include <hip/hip_runtime.h>
#include <hip/hip_bf16.h>

// EDMultiheadRetention: S=128, D=4096, H=32, hd=128
// Pipeline: prep (cast x + kvsT) -> gemm_fused (KS=1, 192x512, BK=128, 32 phases;
//           A dbuf 1-phase-ahead via global_load_lds; W f32 regs 2-phases-ahead;
//           one vmcnt(4)+barrier per phase; fused decay epilogue) -> heads
// R16 vs R10: BK 64->128 (half the sync events, double latency lead); nt reverted.

typedef __bf16 bf16x8 __attribute__((ext_vector_type(8)));
typedef float f32x4 __attribute__((ext_vector_type(4)));

typedef __attribute__((address_space(1))) const unsigned g_u32;
typedef __attribute__((address_space(3))) unsigned l_u32;

static __device__ __forceinline__ f32x4 mfma_bf16(bf16x8 a, bf16x8 b, f32x4 c) {
  return __builtin_amdgcn_mfma_f32_16x16x32_bf16(a, b, c, 0, 0, 0);
}

static __device__ __forceinline__ bf16x8 cvt8(float4 lo, float4 hi) {
  return (bf16x8){(__bf16)lo.x, (__bf16)lo.y, (__bf16)lo.z, (__bf16)lo.w,
                  (__bf16)hi.x, (__bf16)hi.y, (__bf16)hi.z, (__bf16)hi.w};
}

#define WAIT_VM0() asm volatile("s_waitcnt vmcnt(0)" ::: "memory")
#define WAIT_VM4() asm volatile("s_waitcnt vmcnt(4)" ::: "memory")
#define WAIT_LGKM0() asm volatile("s_waitcnt lgkmcnt(0)" ::: "memory")
#define SCHED_FENCE() __builtin_amdgcn_sched_barrier(0)

// ---------------- kernel 1: cast x -> bf16 (blocks 0..255), kvsT prep (256..383)
__global__ __launch_bounds__(256) void prep_kernel(const float* __restrict__ x,
                                                   __bf16* __restrict__ xb,
                                                   const float* __restrict__ kvs,
                                                   const float* __restrict__ alpha,
                                                   __bf16* __restrict__ kvsT) {
  __shared__ float lds[32][129];
  const int tid = threadIdx.x;
  if (blockIdx.x < 256) {
    const int i = (blockIdx.x * 256 + tid) * 8;
    float4 a = *(const float4*)(x + i);
    float4 b = *(const float4*)(x + i + 4);
    *(bf16x8*)(xb + i) = cvt8(a, b);
    return;
  }
  const int bid = blockIdx.x - 256;
  const int h = bid >> 2, dq = bid & 3;
  const int j = tid & 127, dg = tid >> 7;
  const int d0 = dq * 32;
#pragma unroll
  for (int i = 0; i < 16; ++i) {
    const int dloc = dg * 16 + i;
    const int d = d0 + dloc;
    const float dS = exp2f(128.f * log2f(alpha[h * 128 + d]));
    lds[dloc][j] = kvs[(size_t)h * 16384 + d * 128 + j] * dS;
  }
  __syncthreads();
  const int jj = tid >> 1, dh = tid & 1;
  bf16x8 a0, a1;
#pragma unroll
  for (int i = 0; i < 8; ++i) a0[i] = (__bf16)lds[dh * 16 + i][jj];
#pragma unroll
  for (int i = 0; i < 8; ++i) a1[i] = (__bf16)lds[dh * 16 + 8 + i][jj];
  *(bf16x8*)(kvsT + (size_t)h * 16384 + jj * 128 + d0 + dh * 16) = a0;
  *(bf16x8*)(kvsT + (size_t)h * 16384 + jj * 128 + d0 + dh * 16 + 8) = a1;
}

// ---------------- kernel 2: single-pass GEMM + fused decay/layout epilogue ---
// 192 blocks x 512 thr (8 waves: 4 wm x 2 wn). Tile M=128 x N=64, K=4096, BK=128.
// 32 phases; per phase: stage A(P+1) [32KB DMA] + W(P+2) [regs], 16 b128 frag
// reads/lane, 16 MFMA/wave, ds_write B(P+1), ONE vmcnt(4)+lgkm+barrier.
// Rows are 256B = 16 chunks of 16B; phys chunk p = c ^ (row & 15).
__global__ __launch_bounds__(512, 2) void gemm_fused_kernel(const __bf16* __restrict__ xb,
                                                            const float* __restrict__ W,
                                                            const float* __restrict__ alpha,
                                                            __bf16* __restrict__ qd,
                                                            __bf16* __restrict__ kd,
                                                            __bf16* __restrict__ kdT,
                                                            __bf16* __restrict__ vT) {
  __shared__ __bf16 Ald[2][128 * 128];  // 64 KB
  __shared__ __bf16 Bld[2][64 * 128];   // 32 KB

  const int tid = threadIdx.x;
  const int wid = tid >> 6, lane = tid & 63;
  const int r0 = lane & 15, l4 = lane >> 4, rr = l4 << 2;
  const int n0 = blockIdx.x * 64;
  const int wm = wid & 3, wn = wid >> 2;

  // A staging: 4 DMA units/thread; unit u -> (row=u>>4, phys chunk p=u&15),
  // source logical chunk g = p ^ (row&15); LDS dest linear (u*16 B).
  int a_row[4], a_koff[4];
#pragma unroll
  for (int i = 0; i < 4; ++i) {
    const int u = i * 512 + tid;
    a_row[i] = u >> 4;
    a_koff[i] = ((u & 15) ^ (a_row[i] & 15)) << 3;
  }
  // B staging: 64 rows x 8 threads; thread covers logical chunks 2j, 2j+1
  const int b_row = tid >> 3, b_j = tid & 7;
  int b_elem[2];
#pragma unroll
  for (int i = 0; i < 2; ++i)
    b_elem[i] = b_row * 128 + (((2 * b_j + i) ^ (b_row & 15)) << 3);
  const float* wp = W + (size_t)(n0 + b_row) * 4096 + b_j * 16;  // 16 floats/thread

  // fragment read offsets (elements): logical chunk c = kh*4+l4, phys = c^(row&15)
  int a_off[2][4], b_off[2][4];
#pragma unroll
  for (int mf = 0; mf < 2; ++mf)
#pragma unroll
    for (int kh = 0; kh < 4; ++kh) {
      const int row = wm * 32 + mf * 16 + r0;
      const int p = (kh * 4 + l4) ^ (row & 15);
      a_off[mf][kh] = row * 128 + p * 8;
    }
#pragma unroll
  for (int nf = 0; nf < 2; ++nf)
#pragma unroll
    for (int kh = 0; kh < 4; ++kh) {
      const int row = wn * 32 + nf * 16 + r0;
      const int p = (kh * 4 + l4) ^ (row & 15);
      b_off[nf][kh] = row * 128 + p * 8;
    }

  f32x4 acc[2][2];
#pragma unroll
  for (int mf = 0; mf < 2; ++mf)
#pragma unroll
    for (int nf = 0; nf < 2; ++nf) acc[mf][nf] = (f32x4){0.f, 0.f, 0.f, 0.f};

  float4 wA[4], wB[4];  // two W reg sets, 4 float4 each (16 floats = this thread's slice)

#define A_ISSUE(P_, BUF_)                                                        \
  do {                                                                           \
    const int kb_ = (P_) * 128;                                                  \
    char* dst_ = (char*)&Ald[0][0] + (BUF_) * 32768;                             \
    _Pragma("unroll") for (int i = 0; i < 4; ++i) {                              \
      const __bf16* src = xb + a_row[i] * 4096 + kb_ + a_koff[i];                \
      __builtin_amdgcn_global_load_lds((g_u32*)(const void*)src,                 \
          (l_u32*)(void*)(dst_ + i * 8192 + wid * 1024), 16, 0, 0);              \
    }                                                                            \
  } while (0)

#define W_ISSUE(SET, P_)                                                         \
  do {                                                                           \
    const int kb_ = (P_) * 128;                                                  \
    _Pragma("unroll") for (int q = 0; q < 4; ++q)                                \
        SET[q] = *(const float4*)(wp + kb_ + q * 4);                             \
  } while (0)

#define B_WRITE(SET, BUF_)                                                       \
  do {                                                                           \
    *(bf16x8*)(&Bld[BUF_][b_elem[0]]) = cvt8(SET[0], SET[1]);                    \
    *(bf16x8*)(&Bld[BUF_][b_elem[1]]) = cvt8(SET[2], SET[3]);                    \
  } while (0)

  // ---- prologue. FIFO: A(0)4, W(0)4, W(1)4.
  A_ISSUE(0, 0);
  W_ISSUE(wA, 0);
  W_ISSUE(wB, 1);
  WAIT_VM4();  // A(0)+W(0) done; W(1) in flight
  B_WRITE(wA, 0);
  WAIT_LGKM0();
  SCHED_FENCE();
  __builtin_amdgcn_s_barrier();
  SCHED_FENCE();

// Phase P (cur=P&1): issue A(P+1)->1-cur, W(P+2)->LD set; compute from cur;
// wait vmcnt(4) (W(P+1)+A(P+1) landed, W(P+2) in flight); ds_write B(P+1); barrier.
#define GEMM_PHASE(P, CUR, WRSET, LDSET)                                         \
  do {                                                                           \
    const bool hn1 = (P) + 1 < 32, hn2 = (P) + 2 < 32;                           \
    if (hn1) A_ISSUE((P) + 1, 1 - (CUR));                                        \
    if (hn2) W_ISSUE(LDSET, (P) + 2);                                            \
    SCHED_FENCE();                                                               \
    const __bf16* abase_ = &Ald[0][0] + (CUR) * 16384;                           \
    const __bf16* bbase_ = &Bld[0][0] + (CUR) * 8192;                            \
    bf16x8 af[2][4], bfr[2][4];                                                  \
    _Pragma("unroll") for (int kh = 0; kh < 4; ++kh) {                           \
      _Pragma("unroll") for (int mf = 0; mf < 2; ++mf)                           \
          af[mf][kh] = *(const bf16x8*)(abase_ + a_off[mf][kh]);                 \
      _Pragma("unroll") for (int nf = 0; nf < 2; ++nf)                           \
          bfr[nf][kh] = *(const bf16x8*)(bbase_ + b_off[nf][kh]);                \
    }                                                                            \
    _Pragma("unroll") for (int kh = 0; kh < 4; ++kh)                             \
        _Pragma("unroll") for (int mf = 0; mf < 2; ++mf)                         \
            _Pragma("unroll") for (int nf = 0; nf < 2; ++nf)                     \
                acc[mf][nf] = mfma_bf16(af[mf][kh], bfr[nf][kh], acc[mf][nf]);   \
    SCHED_FENCE();                                                               \
    if (hn1) {                                                                   \
      if (hn2) { WAIT_VM4(); } else { WAIT_VM0(); } /* W(P+1)+A(P+1) landed */   \
      B_WRITE(WRSET, 1 - (CUR));                                                 \
      WAIT_LGKM0();                                                              \
      SCHED_FENCE();                                                             \
      __builtin_amdgcn_s_barrier();                                              \
      SCHED_FENCE();                                                             \
    }                                                                            \
  } while (0)

  for (int p = 0; p < 32; p += 2) {
    GEMM_PHASE(p, 0, wB, wA);      // write B(p+1) from wB=W(p+1); wA <- W(p+2)
    GEMM_PHASE(p + 1, 1, wA, wB);  // write B(p+2) from wA; wB <- W(p+3)
  }
#undef GEMM_PHASE
#undef A_ISSUE
#undef W_ISSUE
#undef B_WRITE

  // ---- fused epilogue: acc -> LDS f32 -> decay -> bf16 layouts
  __syncthreads();  // all A/B LDS reads done; safe to repurpose Ald
  float* LDSf = (float*)&Ald[0][0];  // 128 x 64 f32 = 32 KB
#pragma unroll
  for (int mf = 0; mf < 2; ++mf)
#pragma unroll
    for (int nf = 0; nf < 2; ++nf)
#pragma unroll
      for (int r = 0; r < 4; ++r) {
        const int s = wm * 32 + mf * 16 + rr + r;
        const int c = wn * 32 + nf * 16 + r0;
        LDSf[s * 64 + c] = acc[mf][nf][r];
      }
  __syncthreads();

  const int which = n0 >> 12;      // 0=q 1=k 2=v
  const int hd = n0 & 4095;
  const int h = hd >> 7;
  const int db = hd & 127;         // 0 or 64

  if (which < 2) {
    // row-major [h][s][db..db+64): unit u = (s, 8d)
    __bf16* dst = (which == 0 ? qd : kd) + (size_t)h * 16384;
#pragma unroll
    for (int i = 0; i < 2; ++i) {
      const int u = i * 512 + tid;
      const int s = u >> 3, d8 = (u & 7) * 8;
      bf16x8 frag;
#pragma unroll
      for (int j = 0; j < 8; ++j) {
        const float la = log2f(alpha[h * 128 + db + d8 + j]);
        const float e = (which == 0) ? (float)(s - 127) : (float)(127 - s);
        frag[j] = (__bf16)(LDSf[s * 64 + d8 + j] * exp2f(e * la - 6.0f));
      }
      *(bf16x8*)(dst + s * 128 + db + d8) = frag;
    }
  }
  if (which >= 1) {
    // transposed [h][db+d][s]: unit u = (d, 8s)
    __bf16* dstT = (which == 1 ? kdT : vT) + (size_t)h * 16384;
#pragma unroll
    for (int i = 0; i < 2; ++i) {
      const int u = i * 512 + tid;
      const int d = u >> 4, s8 = (u & 15) * 8;
      bf16x8 frag;
      if (which == 1) {
        const float la = log2f(alpha[h * 128 + db + d]);
#pragma unroll
        for (int j = 0; j < 8; ++j)
          frag[j] = (__bf16)(LDSf[(s8 + j) * 64 + d] * exp2f((float)(127 - (s8 + j)) * la - 6.0f));
      } else {
#pragma unroll
        for (int j = 0; j < 8; ++j) frag[j] = (__bf16)LDSf[(s8 + j) * 64 + d];
      }
      *(bf16x8*)(dstT + (db + d) * 128 + s8) = frag;
    }
  }
}

// ---------------- kernel 3: per-head retention (all contiguous bf16 loads) --
// bid<128: out rows; bid>=128: new_kvs rows. 128 threads (2 waves).
__global__ __launch_bounds__(128) void heads_kernel(const __bf16* __restrict__ qd,
                                                    const __bf16* __restrict__ kd,
                                                    const __bf16* __restrict__ kdT,
                                                    const __bf16* __restrict__ vT,
                                                    const __bf16* __restrict__ kvsT,
                                                    const float* __restrict__ kvs,
                                                    const float* __restrict__ alpha,
                                                    float* __restrict__ out) {
  const int bid = blockIdx.x;
  const int tid = threadIdx.x;
  const int wid = tid >> 6, lane = tid & 63;
  const int r0 = lane & 15, l4 = lane >> 4;
  const int g8 = l4 << 3, rr = l4 << 2;

  if (bid < 128) {
    const int h = bid >> 2, w = bid & 3;
    const int m_base = w * 32;
    __shared__ __bf16 attn_s[32][136];
    const __bf16* qh = qd + (size_t)h * 16384;
    const __bf16* kh = kd + (size_t)h * 16384;

    f32x4 acc[2][4];
#pragma unroll
    for (int mf = 0; mf < 2; ++mf)
#pragma unroll
      for (int nf = 0; nf < 4; ++nf) acc[mf][nf] = (f32x4){0.f, 0.f, 0.f, 0.f};

    // phase 1: attn cols wid*64..+64
#pragma unroll
    for (int k0 = 0; k0 < 128; k0 += 32) {
      const int kk = k0 + g8;
      bf16x8 a[2];
#pragma unroll
      for (int mf = 0; mf < 2; ++mf)
        a[mf] = *(const bf16x8*)(qh + (m_base + mf * 16 + r0) * 128 + kk);
#pragma unroll
      for (int nf = 0; nf < 4; ++nf) {
        const int jn = wid * 64 + nf * 16 + r0;
        bf16x8 b = *(const bf16x8*)(kh + jn * 128 + kk);
#pragma unroll
        for (int mf = 0; mf < 2; ++mf) acc[mf][nf] = mfma_bf16(a[mf], b, acc[mf][nf]);
      }
    }
#pragma unroll
    for (int mf = 0; mf < 2; ++mf)
#pragma unroll
      for (int nf = 0; nf < 4; ++nf)
#pragma unroll
        for (int r = 0; r < 4; ++r) {
          const int i = m_base + mf * 16 + rr + r;
          const int j = wid * 64 + nf * 16 + r0;
          attn_s[mf * 16 + rr + r][j] = (__bf16)((j <= i) ? acc[mf][nf][r] : 0.f);
        }
    __syncthreads();

    // phase 2: out = gelu(attn @ v + q @ kvsT), d2 in wid*64..+64
#pragma unroll
    for (int mf = 0; mf < 2; ++mf)
#pragma unroll
      for (int nf = 0; nf < 4; ++nf) acc[mf][nf] = (f32x4){0.f, 0.f, 0.f, 0.f};
    const __bf16* vTh = vT + (size_t)h * 16384;
    const __bf16* kvsTh = kvsT + (size_t)h * 16384;
#pragma unroll
    for (int k0 = 0; k0 < 128; k0 += 32) {
      const int kk = k0 + g8;
      bf16x8 a[2];
#pragma unroll
      for (int mf = 0; mf < 2; ++mf)
        a[mf] = *(const bf16x8*)(&attn_s[mf * 16 + r0][kk]);
#pragma unroll
      for (int nf = 0; nf < 4; ++nf) {
        const int d2 = wid * 64 + nf * 16 + r0;
        bf16x8 b = *(const bf16x8*)(vTh + d2 * 128 + kk);
#pragma unroll
        for (int mf = 0; mf < 2; ++mf) acc[mf][nf] = mfma_bf16(a[mf], b, acc[mf][nf]);
      }
    }
#pragma unroll
    for (int k0 = 0; k0 < 128; k0 += 32) {
      const int kk = k0 + g8;
      bf16x8 a[2];
#pragma unroll
      for (int mf = 0; mf < 2; ++mf)
        a[mf] = *(const bf16x8*)(qh + (m_base + mf * 16 + r0) * 128 + kk);
#pragma unroll
      for (int nf = 0; nf < 4; ++nf) {
        const int d2 = wid * 64 + nf * 16 + r0;
        bf16x8 b = *(const bf16x8*)(kvsTh + d2 * 128 + kk);
#pragma unroll
        for (int mf = 0; mf < 2; ++mf) acc[mf][nf] = mfma_bf16(a[mf], b, acc[mf][nf]);
      }
    }
#pragma unroll
    for (int mf = 0; mf < 2; ++mf)
#pragma unroll
      for (int nf = 0; nf < 4; ++nf)
#pragma unroll
        for (int r = 0; r < 4; ++r) {
          const int s = m_base + mf * 16 + rr + r;
          const int d2 = wid * 64 + nf * 16 + r0;
          const float y = acc[mf][nf][r];
          const float u = 0.7978845608028654f * (y + 0.044715f * y * y * y);
          out[(size_t)s * 4096 + h * 128 + d2] = 0.5f * y * (1.f + tanhf(u));
        }
  } else {
    const int b2 = bid - 128;
    const int h = b2 >> 2, w = b2 & 3;
    const int m_base = w * 32;
    const __bf16* kTh = kdT + (size_t)h * 16384;
    const __bf16* vTh = vT + (size_t)h * 16384;

    f32x4 acc[2][4];
#pragma unroll
    for (int mf = 0; mf < 2; ++mf)
#pragma unroll
      for (int nf = 0; nf < 4; ++nf) acc[mf][nf] = (f32x4){0.f, 0.f, 0.f, 0.f};
#pragma unroll
    for (int k0 = 0; k0 < 128; k0 += 32) {
      const int kk = k0 + g8;
      bf16x8 a[2];
#pragma unroll
      for (int mf = 0; mf < 2; ++mf)
        a[mf] = *(const bf16x8*)(kTh + (m_base + mf * 16 + r0) * 128 + kk);
#pragma unroll
      for (int nf = 0; nf < 4; ++nf) {
        const int j = wid * 64 + nf * 16 + r0;
        bf16x8 b = *(const bf16x8*)(vTh + j * 128 + kk);
#pragma unroll
        for (int mf = 0; mf < 2; ++mf) acc[mf][nf] = mfma_bf16(a[mf], b, acc[mf][nf]);
      }
    }
#pragma unroll
    for (int mf = 0; mf < 2; ++mf)
#pragma unroll
      for (int nf = 0; nf < 4; ++nf)
#pragma unroll
        for (int r = 0; r < 4; ++r) {
          const int i = m_base + mf * 16 + rr + r;
          const int j = wid * 64 + nf * 16 + r0;
          const float dSi = exp2f(128.f * log2f(alpha[h * 128 + i]));
          const float val = acc[mf][nf][r] + kvs[(size_t)h * 16384 + i * 128 + j] * dSi;
          out[524288 + (size_t)h * 16384 + i * 128 + j] = val;
        }
  }
}

extern "C" void kernel_launch(void* const* d_in, const int* in_sizes, int n_in,
                              void* d_out, int out_size, void* d_ws, size_t ws_size,
                              hipStream_t stream) {
  const float* x = (const float*)d_in[0];      // (128, 4096)
  const float* W = (const float*)d_in[1];      // (12288, 4096)
  const float* alpha = (const float*)d_in[2];  // (32, 128)
  const float* kvs = (const float*)d_in[3];    // (32, 128, 128)
  float* out = (float*)d_out;

  char* ws = (char*)d_ws;
  __bf16* xb = (__bf16*)ws;                      // 1 MB
  __bf16* qd = (__bf16*)(ws + (1u << 20));       // 1 MB each
  __bf16* kd = (__bf16*)(ws + 2u * (1u << 20));
  __bf16* kdT = (__bf16*)(ws + 3u * (1u << 20));
  __bf16* vT = (__bf16*)(ws + 4u * (1u << 20));
  __bf16* kvsT = (__bf16*)(ws + 5u * (1u << 20));

  prep_kernel<<<384, 256, 0, stream>>>(x, xb, kvs, alpha, kvsT);
  gemm_fused_kernel<<<192, 512, 0, stream>>>(xb, W, alpha, qd, kd, kdT, vT);
  heads_kernel<<<256, 128, 0, stream>>>(qd, kd, kdT, vT, kvsT, kvs, alpha, out);
}